// Round 12
// baseline (1249.475 us; speedup 1.0000x reference)
//
#include <hip/hip_runtime.h>
#include <hip/hip_bf16.h>
#include <cstddef>

#define LN_EPS 1e-3f

typedef short bf16x8 __attribute__((ext_vector_type(8)));
typedef float f32x4 __attribute__((ext_vector_type(4)));

__device__ __forceinline__ unsigned short f2bf(float f) {
    __hip_bfloat16 b = __float2bfloat16(f);
    unsigned short u;
    __builtin_memcpy(&u, &b, 2);
    return u;
}

__device__ __forceinline__ float bf2f(short u) {
    unsigned int x = ((unsigned int)(unsigned short)u) << 16;
    float f;
    __builtin_memcpy(&f, &x, 4);
    return f;
}

__device__ __forceinline__ float hsig(float x) {
    return fminf(fmaxf(fmaf(x, 0.2f, 0.5f), 0.f), 1.f);
}

// ---------------------------------------------------------------------------
// LayerNorm over last dim C=16, fp32 in -> bf16 out (one thread per row)
// ---------------------------------------------------------------------------
__global__ void ln16_kernel(const float* __restrict__ x, const float* __restrict__ g,
                            const float* __restrict__ b, short* __restrict__ y, int rows)
{
    int r = blockIdx.x * 256 + threadIdx.x;
    if (r >= rows) return;
    const float4* xr = (const float4*)(x + (size_t)r * 16);
    float v[16];
    *(float4*)(v + 0)  = xr[0];
    *(float4*)(v + 4)  = xr[1];
    *(float4*)(v + 8)  = xr[2];
    *(float4*)(v + 12) = xr[3];
    float mu = 0.f;
    #pragma unroll
    for (int i = 0; i < 16; ++i) mu += v[i];
    mu *= (1.f / 16.f);
    float var = 0.f;
    #pragma unroll
    for (int i = 0; i < 16; ++i) { float d = v[i] - mu; var += d * d; }
    var *= (1.f / 16.f);
    float rs = rsqrtf(var + LN_EPS);
    union { bf16x8 v8; unsigned short u[8]; } p0, p1;
    #pragma unroll
    for (int i = 0; i < 8; ++i)  p0.u[i] = f2bf((v[i] - mu) * rs * g[i] + b[i]);
    #pragma unroll
    for (int i = 0; i < 8; ++i)  p1.u[i] = f2bf((v[8 + i] - mu) * rs * g[8 + i] + b[8 + i]);
    bf16x8* yr = (bf16x8*)(y + (size_t)r * 16);
    yr[0] = p0.v8;
    yr[1] = p1.v8;
}

// ---------------------------------------------------------------------------
// Weight prep with GATE-INTERLEAVED cout permutation:
//   co' = q*64 + wn*32 + gate*8 + fl  <-  co_orig = gate*64 + (q*16+wn*8+fl)
// fp32 [K][256] -> bf16 [chunk][256 co'][32 k], zero-padded k >= K.
// ---------------------------------------------------------------------------
__global__ void prep_w_perm(const float* __restrict__ w, short* __restrict__ o, int K, int NC)
{
    int e = blockIdx.x * 256 + threadIdx.x;
    int tot = NC * 32 * 256;
    if (e >= tot) return;
    int cop = e & 255;
    int k   = e >> 8;
    int qq   = cop >> 6;
    int wn   = (cop >> 5) & 1;
    int gate = (cop >> 3) & 3;
    int fl   = cop & 7;
    int fg = qq * 16 + wn * 8 + fl;
    int co_orig = gate * 64 + fg;
    float v = (k < K) ? w[(size_t)k * 256 + co_orig] : 0.f;
    int chunk = k >> 5, kk = k & 31;
    o[((size_t)chunk * 256 + cop) * 32 + kk] = (short)f2bf(v);
}

// ---------------------------------------------------------------------------
// Stage bf16 patch rows [0,PRN): global bf16 -> bf16 XOR-swizzled LDS.
// DOLN: fused LayerNorm-64 (8-lane octet shfl stats). Requires TOTG % 256 == 0
// when DOLN (holds: LSTM2 phase1 8*36*8 = 2304).
// ---------------------------------------------------------------------------
template<int CIN, int PAD, int PRN, int PW, bool ZEROROW, bool DOLN>
__device__ __forceinline__ void stage_patch(char* smem, const short* __restrict__ inN,
                                            int IH, int IW, int r0,
                                            const float* __restrict__ lg,
                                            const float* __restrict__ lb)
{
    constexpr int GPP = CIN / 8;
    constexpr int SH  = (CIN == 64) ? 7 : 6;
    constexpr int TOTG = PRN * PW * GPP;
    const int tid = threadIdx.x;
    for (int gg = tid; gg < TOTG; gg += 256) {
        int pix = gg / GPP;
        int cig = gg % GPP;
        int pr = pix / PW, pc = pix % PW;
        int gy = r0 - PAD + pr;
        int gx = pc - PAD;
        bool ok = (gy >= 0) & (gy < IH) & (gx >= 0) & (gx < IW);
        if (ZEROROW && pr == PRN - 1) ok = false;   // zero row for K-pad taps
        bf16x8 v;
        #pragma unroll
        for (int i = 0; i < 8; ++i) v[i] = 0;
        if (ok) v = *(const bf16x8*)(inN + ((size_t)gy * IW + gx) * CIN + cig * 8);
        if (DOLN) {
            float f[8];
            #pragma unroll
            for (int i = 0; i < 8; ++i) f[i] = bf2f(v[i]);
            float s = 0.f;
            #pragma unroll
            for (int i = 0; i < 8; ++i) s += f[i];
            s += __shfl_xor(s, 1); s += __shfl_xor(s, 2); s += __shfl_xor(s, 4);
            float mu = s * (1.f / 64.f);
            float q = 0.f;
            #pragma unroll
            for (int i = 0; i < 8; ++i) { float d = f[i] - mu; q += d * d; }
            q += __shfl_xor(q, 1); q += __shfl_xor(q, 2); q += __shfl_xor(q, 4);
            float rs = rsqrtf(q * (1.f / 64.f) + LN_EPS);
            union { bf16x8 v8; unsigned short u[8]; } pk;
            #pragma unroll
            for (int i = 0; i < 8; ++i) {
                int ch = cig * 8 + i;
                pk.u[i] = f2bf((f[i] - mu) * rs * lg[ch] + lb[ch]);
            }
            v = pk.v8;
        }
        int ad = (pix * CIN + cig * 8) * 2;
        ad ^= ((ad >> SH) & 7) << 4;
        *(bf16x8*)(smem + ad) = v;
    }
}

// ---------------------------------------------------------------------------
// K-loop over NC chunks: A-frags from swizzled LDS, B-frags global->reg with
// DEPTH-4 chunk prefetch in 4 named register slots (static indexing; tails
// handled by wave-uniform runtime guards). No barriers.
// ---------------------------------------------------------------------------
template<int CIN, int PW, int NC>
__device__ __forceinline__ void kloop(const char* smem, const short* __restrict__ wbase,
                                      int colane, int g, const int* base_m, f32x4 (&acc)[4][2])
{
    constexpr int SH = (CIN == 64) ? 7 : 6;
    const short* wlp = wbase + (size_t)colane * 32 + g * 8;

    bf16x8 ba[4], bb[4];
    #pragma unroll
    for (int j = 0; j < 4; ++j) {
        if (j < NC) {
            ba[j] = *(const bf16x8*)(wlp + (size_t)j * 8192);
            bb[j] = *(const bf16x8*)(wlp + (size_t)j * 8192 + 512);
        }
    }

    int dy0 = 0, dx0 = 0, dy1 = 0, dx1 = 1;
    for (int cb = 0; cb < NC; cb += 4) {
        #pragma unroll
        for (int j = 0; j < 4; ++j) {
            const int c = cb + j;
            if (c < NC) {
                int off;
                if (CIN == 64) {
                    off = (dy0 * PW + dx0) * 128 + ((c & 1) << 6) + (g << 4);
                } else {
                    int U0 = (dy0 * PW + dx0) * 32;
                    int U1 = (dy1 * PW + dx1) * 32;
                    off = ((g & 2) ? U1 : U0) + ((g & 1) << 4);
                }
                bf16x8 a[4];
                #pragma unroll
                for (int m = 0; m < 4; ++m) {
                    int ad = base_m[m] + off;
                    ad ^= ((ad >> SH) & 7) << 4;
                    a[m] = *(const bf16x8*)(smem + ad);
                }
                #pragma unroll
                for (int m = 0; m < 4; ++m) {
                    acc[m][0] = __builtin_amdgcn_mfma_f32_16x16x32_bf16(a[m], ba[j], acc[m][0], 0, 0, 0);
                    acc[m][1] = __builtin_amdgcn_mfma_f32_16x16x32_bf16(a[m], bb[j], acc[m][1], 0, 0, 0);
                }
                if (c + 4 < NC) {   // refill slot j, 4 chunks ahead
                    const short* wnx = wlp + (size_t)(c + 4) * 8192;
                    ba[j] = *(const bf16x8*)wnx;
                    bb[j] = *(const bf16x8*)(wnx + 512);
                }
                if (CIN == 64) {
                    if (c & 1) { if (++dx0 == 5) { dx0 = 0; ++dy0; } }
                } else {
                    dx0 += 2; if (dx0 >= 5) { dx0 -= 5; ++dy0; }
                    dx1 += 2; if (dx1 >= 5) { dx1 -= 5; ++dy1; }
                }
            }
        }
    }
}

// ---------------------------------------------------------------------------
// One full ConvLSTM step for a (128px x 64co') tile with FUSED GATES:
//   phase1 (DOLN1 optionally fuses LayerNorm-64): W-conv ; phase2: U-conv.
//   epilogue: gate exchange via shfl_xor(8); c fp32, h bf16.
// ---------------------------------------------------------------------------
template<int CIN1, int PAD1, int NC1, int PRN1, bool ZR1, bool DOLN1,
         int NC2, int PRN2, int OW, int OH>
__device__ void lstm_step_core(int lblk, const short* __restrict__ in1, size_t in1_bstride,
                               int IH1, int IW1,
                               const short* __restrict__ hprev,
                               const short* __restrict__ wts, const float* __restrict__ bias,
                               const float* __restrict__ lg, const float* __restrict__ lb,
                               float* __restrict__ cbuf, short* __restrict__ hbuf,
                               int has_rec, char* smem)
{
    constexpr int PW  = OW + 4;
    constexpr int OHW = OW * OH;
    constexpr int NTIL = (OHW + 127) / 128;
    constexpr bool FULL = (OHW % 128) == 0;

    const int tid  = threadIdx.x;
    const int tile = lblk % NTIL;
    const int q    = (lblk / NTIL) & 3;
    const int n    = lblk / (NTIL * 4);
    const int p0   = tile * 128;
    const int r0   = p0 / OW;
    const int co0  = q * 64;

    const int lane = tid & 63;
    const int wid  = tid >> 6;
    const int wm   = wid >> 1;
    const int wn   = wid & 1;
    const int lr   = lane & 15;
    const int g    = lane >> 4;

    int base1[4], base2[4];
    #pragma unroll
    for (int m = 0; m < 4; ++m) {
        int px = p0 + wm * 64 + m * 16 + lr;
        int r = px / OW;
        int x = px - r * OW;
        base1[m] = ((r - r0) * PW + x) * CIN1 * 2;
        base2[m] = ((r - r0) * PW + x) * 128;
    }

    f32x4 acc[4][2];
    #pragma unroll
    for (int m = 0; m < 4; ++m)
        #pragma unroll
        for (int nn = 0; nn < 2; ++nn)
            acc[m][nn] = (f32x4){0.f, 0.f, 0.f, 0.f};

    // ---- phase 1: W-conv (optionally with fused LN on the staged input) ----
    stage_patch<CIN1, PAD1, PRN1, PW, ZR1, DOLN1>(
        smem, in1 + (size_t)n * in1_bstride, IH1, IW1, r0, lg, lb);
    __syncthreads();
    kloop<CIN1, PW, NC1>(smem, wts, co0 + wn * 32 + lr, g, base1, acc);

    // ---- phase 2: U-conv on previous h (restage same LDS) ----
    if (has_rec) {
        __syncthreads();
        stage_patch<64, 2, PRN2, PW, false, false>(
            smem, hprev + (size_t)n * OHW * 64, OH, OW, r0, nullptr, nullptr);
        __syncthreads();
        kloop<64, PW, NC2>(smem, wts + (size_t)NC1 * 8192, co0 + wn * 32 + lr, g, base2, acc);
    }

    // ---- fused gate epilogue ----
    const int fg = q * 16 + wn * 8 + (lr & 7);
    const bool low = (lr & 8) == 0;
    const float b0  = bias[(lr >> 3) * 64 + fg];         // gate 0/1 (i or f)
    const float b1v = bias[(2 + (lr >> 3)) * 64 + fg];   // gate 2/3 (cg or o)
    float* cN = cbuf + (size_t)n * OHW * 64;
    short* hN = hbuf + (size_t)n * OHW * 64;
    #pragma unroll
    for (int m = 0; m < 4; ++m) {
        int pxb = p0 + wm * 64 + m * 16 + g * 4;
        #pragma unroll
        for (int j = 0; j < 4; ++j) {
            int px = pxb + j;
            float a0 = acc[m][0][j] + b0;
            float a1 = acc[m][1][j] + b1v;
            float q0 = __shfl_xor(a0, 8);
            float q1 = __shfl_xor(a1, 8);
            float iv  = low ? a0 : q0;
            float fv  = low ? q0 : a0;
            float cgv = low ? a1 : q1;
            float ov  = low ? q1 : a1;
            bool valid = FULL || (px < OHW);
            int addr = px * 64 + fg;
            float cp = 0.f;
            if (has_rec && valid) cp = cN[addr];
            float cn = fmaf(hsig(fv), cp, hsig(iv) * tanhf(cgv));
            float hv = hsig(ov) * tanhf(cn);
            if (valid) {
                if (low) cN[addr] = cn;
                else     hN[addr] = (short)f2bf(hv);
            }
        }
    }
}

// ---------------------------------------------------------------------------
// Merged step kernel: blocks [0,n2) = LSTM2 step t (reads LN(h1) inline);
// blocks [n2,...) = LSTM1 step t+1.
// ---------------------------------------------------------------------------
__global__ __launch_bounds__(256, 3) void step_kernel(
    int n2, int has1, int has2,
    const short* __restrict__ h1r, const short* __restrict__ h2r, short* __restrict__ h2w,
    float* __restrict__ c2, const short* __restrict__ w2c, const float* __restrict__ b2,
    const float* __restrict__ lg2, const float* __restrict__ lb2,
    const short* __restrict__ xlnt, short* __restrict__ h1w,
    float* __restrict__ c1, const short* __restrict__ w1c, const float* __restrict__ b1)
{
    __shared__ __align__(16) char smem[46080];
    int bid = blockIdx.x;
    if (bid < n2) {
        // LSTM2: phase1 = W2 on LN(h1(t)) (36x36 VALID -> 32x32), phase2 = U2 on h2
        lstm_step_core<64, 0, 50, 8, false, true, 50, 8, 32, 32>(
            bid, h1r, 82944, 36, 36, h2r, w2c, b2, lg2, lb2, c2, h2w, has2, smem);
    } else {
        // LSTM1: phase1 = W1 on xln frame (40x40 VALID -> 36x36), phase2 = U1 on h1
        lstm_step_core<16, 0, 13, 10, true, false, 50, 9, 36, 36>(
            bid - n2, xlnt, 409600, 40, 40, h1r, w1c, b1, nullptr, nullptr,
            c1, h1w, has1, smem);
    }
}

// ---------------------------------------------------------------------------
// Final: mean over 32x32 pixels (bf16 h), dot dw[64], +db, *0.1
// ---------------------------------------------------------------------------
__global__ void pool_dot_kernel(const short* __restrict__ h, const float* __restrict__ dw,
                                const float* __restrict__ db, float* __restrict__ out)
{
    int b = blockIdx.x;
    __shared__ float sdw[64];
    if (threadIdx.x < 64) sdw[threadIdx.x] = dw[threadIdx.x];
    __syncthreads();
    float partial = 0.f;
    const short* hb = h + (size_t)b * 1024 * 64;
    for (int p = threadIdx.x; p < 1024; p += 256) {
        const short* hp = hb + (size_t)p * 64;
        #pragma unroll
        for (int f = 0; f < 64; f += 8) {
            bf16x8 hv = *(const bf16x8*)(hp + f);
            #pragma unroll
            for (int i = 0; i < 8; ++i) partial += bf2f(hv[i]) * sdw[f + i];
        }
    }
    #pragma unroll
    for (int o = 32; o > 0; o >>= 1) partial += __shfl_xor(partial, o);
    __shared__ float ws[4];
    if ((threadIdx.x & 63) == 0) ws[threadIdx.x >> 6] = partial;
    __syncthreads();
    if (threadIdx.x == 0) {
        float tot = ws[0] + ws[1] + ws[2] + ws[3];
        out[b] = (tot * (1.f / 1024.f) + db[0]) * 0.1f;
    }
}

// ---------------------------------------------------------------------------
// Orchestration: A(0) -> [ M(t) = LSTM2(t) + LSTM1(t+1) ] x15 -> C(15) -> pool.
// ONE launch per step (LN64 fused into LSTM2 staging).
// ---------------------------------------------------------------------------
extern "C" void kernel_launch(void* const* d_in, const int* in_sizes, int n_in,
                              void* d_out, int out_size, void* d_ws, size_t ws_size,
                              hipStream_t stream)
{
    const float* x   = (const float*)d_in[0];
    const float* lg1 = (const float*)d_in[1];
    const float* lb1 = (const float*)d_in[2];
    const float* W1  = (const float*)d_in[3];
    const float* U1  = (const float*)d_in[4];
    const float* b1  = (const float*)d_in[5];
    const float* lg2 = (const float*)d_in[6];
    const float* lb2 = (const float*)d_in[7];
    const float* W2  = (const float*)d_in[8];
    const float* U2  = (const float*)d_in[9];
    const float* b2  = (const float*)d_in[10];
    const float* dw  = (const float*)d_in[11];
    const float* db  = (const float*)d_in[12];
    float* out = (float*)d_out;

    constexpr int B = 8, T = 16;
    constexpr int P1 = 36 * 36, P2 = 32 * 32;

    char* wsb = (char*)d_ws;
    size_t off = 0;
    auto alloc_s = [&](size_t nshort) { short* p = (short*)(wsb + off); off += nshort * 2; return p; };
    auto alloc_f = [&](size_t nfloat) { off = (off + 15) & ~(size_t)15; float* p = (float*)(wsb + off); off += nfloat * 4; return p; };

    short* xln = alloc_s((size_t)B * T * 40 * 40 * 16);   // bf16, 6.5 MB
    short* h1a = alloc_s((size_t)B * P1 * 64);
    short* h1b = alloc_s((size_t)B * P1 * 64);
    short* h2a = alloc_s((size_t)B * P2 * 64);
    short* h2b = alloc_s((size_t)B * P2 * 64);
    short* w1c = alloc_s((size_t)63 * 8192);              // 13 W1 + 50 U1 chunks
    short* w2c = alloc_s((size_t)100 * 8192);             // 50 W2 + 50 U2 chunks
    float* c1  = alloc_f((size_t)B * P1 * 64);
    float* c2  = alloc_f((size_t)B * P2 * 64);
    // total ~20 MB

    short* h1buf[2] = { h1a, h1b };
    short* h2buf[2] = { h2a, h2b };

    // one-time transforms
    ln16_kernel<<<800, 256, 0, stream>>>(x, lg1, lb1, xln, 204800);
    prep_w_perm<<<416, 256, 0, stream>>>(W1, w1c, 400, 13);
    prep_w_perm<<<1600, 256, 0, stream>>>(U1, w1c + (size_t)13 * 8192, 1600, 50);
    prep_w_perm<<<1600, 256, 0, stream>>>(W2, w2c, 1600, 50);
    prep_w_perm<<<1600, 256, 0, stream>>>(U2, w2c + (size_t)50 * 8192, 1600, 50);

    constexpr int NB1 = 11 * 4 * B;   // 352 LSTM1 blocks
    constexpr int NB2 = 8 * 4 * B;    // 256 LSTM2 blocks

    // A(0): LSTM1 step 0 only
    step_kernel<<<NB1, 256, 0, stream>>>(
        0, 0, 0,
        h1buf[1], h2buf[1], h2buf[0], c2, w2c, b2, lg2, lb2,
        xln, h1buf[0], c1, w1c, b1);

    // M(t): LSTM2 step t (reads LN(h1(t)) inline) + LSTM1 step t+1
    for (int t = 0; t < T - 1; ++t) {
        step_kernel<<<NB2 + NB1, 256, 0, stream>>>(
            NB2, 1, (t > 0) ? 1 : 0,
            h1buf[t & 1], h2buf[(t + 1) & 1], h2buf[t & 1], c2, w2c, b2, lg2, lb2,
            xln + (size_t)(t + 1) * 25600, h1buf[(t + 1) & 1], c1, w1c, b1);
    }

    // C(15): LSTM2 final step (h1(15) is in h1buf[1])
    step_kernel<<<NB2, 256, 0, stream>>>(
        NB2, 1, 1,
        h1buf[1], h2buf[0], h2buf[1], c2, w2c, b2, lg2, lb2,
        xln, h1buf[0], c1, w1c, b1);

    pool_dot_kernel<<<B, 256, 0, stream>>>(h2buf[1], dw, db, out);
}

// Round 13
// 851.064 us; speedup vs baseline: 1.4681x; 1.4681x over previous
//
#include <hip/hip_runtime.h>
#include <hip/hip_bf16.h>
#include <cstddef>

#define LN_EPS 1e-3f

typedef short bf16x8 __attribute__((ext_vector_type(8)));
typedef float f32x4 __attribute__((ext_vector_type(4)));

__device__ __forceinline__ unsigned short f2bf(float f) {
    __hip_bfloat16 b = __float2bfloat16(f);
    unsigned short u;
    __builtin_memcpy(&u, &b, 2);
    return u;
}

__device__ __forceinline__ float bf2f(short u) {
    unsigned int x = ((unsigned int)(unsigned short)u) << 16;
    float f;
    __builtin_memcpy(&f, &x, 4);
    return f;
}

__device__ __forceinline__ float hsig(float x) {
    return fminf(fmaxf(fmaf(x, 0.2f, 0.5f), 0.f), 1.f);
}

// Fast tanh: 1 - 2/(e^{2x}+1). __expf -> v_exp_f32; rcp -> v_rcp_f32.
// Clamp +-15 avoids inf/inf (tanh(15) == 1 to 1e-13). Abs err ~1e-6.
__device__ __forceinline__ float tanh_fast(float x) {
    float xc = fminf(fmaxf(x, -15.f), 15.f);
    float t = __expf(2.f * xc);
    return 1.f - 2.f * __builtin_amdgcn_rcpf(t + 1.f);
}

// ---------------------------------------------------------------------------
// LayerNorm over last dim C=16, fp32 in -> bf16 out (one thread per row)
// ---------------------------------------------------------------------------
__global__ void ln16_kernel(const float* __restrict__ x, const float* __restrict__ g,
                            const float* __restrict__ b, short* __restrict__ y, int rows)
{
    int r = blockIdx.x * 256 + threadIdx.x;
    if (r >= rows) return;
    const float4* xr = (const float4*)(x + (size_t)r * 16);
    float v[16];
    *(float4*)(v + 0)  = xr[0];
    *(float4*)(v + 4)  = xr[1];
    *(float4*)(v + 8)  = xr[2];
    *(float4*)(v + 12) = xr[3];
    float mu = 0.f;
    #pragma unroll
    for (int i = 0; i < 16; ++i) mu += v[i];
    mu *= (1.f / 16.f);
    float var = 0.f;
    #pragma unroll
    for (int i = 0; i < 16; ++i) { float d = v[i] - mu; var += d * d; }
    var *= (1.f / 16.f);
    float rs = rsqrtf(var + LN_EPS);
    union { bf16x8 v8; unsigned short u[8]; } p0, p1;
    #pragma unroll
    for (int i = 0; i < 8; ++i)  p0.u[i] = f2bf((v[i] - mu) * rs * g[i] + b[i]);
    #pragma unroll
    for (int i = 0; i < 8; ++i)  p1.u[i] = f2bf((v[8 + i] - mu) * rs * g[8 + i] + b[8 + i]);
    bf16x8* yr = (bf16x8*)(y + (size_t)r * 16);
    yr[0] = p0.v8;
    yr[1] = p1.v8;
}

// ---------------------------------------------------------------------------
// Weight prep with GATE-INTERLEAVED cout permutation:
//   co' = q*64 + wn*32 + gate*8 + fl  <-  co_orig = gate*64 + (q*16+wn*8+fl)
// fp32 [K][256] -> bf16 [chunk][256 co'][32 k], zero-padded k >= K.
// ---------------------------------------------------------------------------
__global__ void prep_w_perm(const float* __restrict__ w, short* __restrict__ o, int K, int NC)
{
    int e = blockIdx.x * 256 + threadIdx.x;
    int tot = NC * 32 * 256;
    if (e >= tot) return;
    int cop = e & 255;
    int k   = e >> 8;
    int qq   = cop >> 6;
    int wn   = (cop >> 5) & 1;
    int gate = (cop >> 3) & 3;
    int fl   = cop & 7;
    int fg = qq * 16 + wn * 8 + fl;
    int co_orig = gate * 64 + fg;
    float v = (k < K) ? w[(size_t)k * 256 + co_orig] : 0.f;
    int chunk = k >> 5, kk = k & 31;
    o[((size_t)chunk * 256 + cop) * 32 + kk] = (short)f2bf(v);
}

// ---------------------------------------------------------------------------
// Stage bf16 patch rows [0,PRN): global bf16 -> bf16 XOR-swizzled LDS.
// DOLN: fused LayerNorm-64 (8-lane octet shfl stats). Requires TOTG % 256 == 0
// when DOLN (holds: LSTM2 phase1 8*36*8 = 2304).
// ---------------------------------------------------------------------------
template<int CIN, int PAD, int PRN, int PW, bool ZEROROW, bool DOLN>
__device__ __forceinline__ void stage_patch(char* smem, const short* __restrict__ inN,
                                            int IH, int IW, int r0,
                                            const float* __restrict__ lg,
                                            const float* __restrict__ lb)
{
    constexpr int GPP = CIN / 8;
    constexpr int SH  = (CIN == 64) ? 7 : 6;
    constexpr int TOTG = PRN * PW * GPP;
    const int tid = threadIdx.x;
    for (int gg = tid; gg < TOTG; gg += 256) {
        int pix = gg / GPP;
        int cig = gg % GPP;
        int pr = pix / PW, pc = pix % PW;
        int gy = r0 - PAD + pr;
        int gx = pc - PAD;
        bool ok = (gy >= 0) & (gy < IH) & (gx >= 0) & (gx < IW);
        if (ZEROROW && pr == PRN - 1) ok = false;   // zero row for K-pad taps
        bf16x8 v;
        #pragma unroll
        for (int i = 0; i < 8; ++i) v[i] = 0;
        if (ok) v = *(const bf16x8*)(inN + ((size_t)gy * IW + gx) * CIN + cig * 8);
        if (DOLN) {
            float f[8];
            #pragma unroll
            for (int i = 0; i < 8; ++i) f[i] = bf2f(v[i]);
            float s = 0.f;
            #pragma unroll
            for (int i = 0; i < 8; ++i) s += f[i];
            s += __shfl_xor(s, 1); s += __shfl_xor(s, 2); s += __shfl_xor(s, 4);
            float mu = s * (1.f / 64.f);
            float q = 0.f;
            #pragma unroll
            for (int i = 0; i < 8; ++i) { float d = f[i] - mu; q += d * d; }
            q += __shfl_xor(q, 1); q += __shfl_xor(q, 2); q += __shfl_xor(q, 4);
            float rs = rsqrtf(q * (1.f / 64.f) + LN_EPS);
            union { bf16x8 v8; unsigned short u[8]; } pk;
            #pragma unroll
            for (int i = 0; i < 8; ++i) {
                int ch = cig * 8 + i;
                pk.u[i] = f2bf((f[i] - mu) * rs * lg[ch] + lb[ch]);
            }
            v = pk.v8;
        }
        int ad = (pix * CIN + cig * 8) * 2;
        ad ^= ((ad >> SH) & 7) << 4;
        *(bf16x8*)(smem + ad) = v;
    }
}

// ---------------------------------------------------------------------------
// K-loop over NC chunks: A-frags from swizzled LDS, B-frags global->reg with
// DEPTH-2 chunk prefetch ([chunk][co'][32k] == B-frag layout). No barriers.
// (Reverted from depth-4: 4 slots spilled to scratch, +41 MB HBM, -44% perf.)
// ---------------------------------------------------------------------------
template<int CIN, int PW, int NC>
__device__ __forceinline__ void kloop(const char* smem, const short* __restrict__ wbase,
                                      int colane, int g, const int* base_m, f32x4 (&acc)[4][2])
{
    constexpr int SH = (CIN == 64) ? 7 : 6;
    const short* wlp = wbase + (size_t)colane * 32 + g * 8;
    bf16x8 c0a = *(const bf16x8*)wlp;
    bf16x8 c0b = *(const bf16x8*)(wlp + 512);
    bf16x8 c1a, c1b;
    if (NC > 1) {
        c1a = *(const bf16x8*)(wlp + 8192);
        c1b = *(const bf16x8*)(wlp + 8192 + 512);
    }
    int dy0 = 0, dx0 = 0, dy1 = 0, dx1 = 1;
    for (int c = 0; c < NC; ++c) {
        bf16x8 n2a, n2b;
        const bool pf = (c + 2 < NC);
        if (pf) {
            const short* wnx = wlp + (size_t)(c + 2) * 8192;
            n2a = *(const bf16x8*)wnx;
            n2b = *(const bf16x8*)(wnx + 512);
        }
        int off;
        if (CIN == 64) {
            off = (dy0 * PW + dx0) * 128 + ((c & 1) << 6) + (g << 4);
        } else {
            int U0 = (dy0 * PW + dx0) * 32;
            int U1 = (dy1 * PW + dx1) * 32;
            off = ((g & 2) ? U1 : U0) + ((g & 1) << 4);
        }
        bf16x8 a[4];
        #pragma unroll
        for (int m = 0; m < 4; ++m) {
            int ad = base_m[m] + off;
            ad ^= ((ad >> SH) & 7) << 4;
            a[m] = *(const bf16x8*)(smem + ad);
        }
        #pragma unroll
        for (int m = 0; m < 4; ++m) {
            acc[m][0] = __builtin_amdgcn_mfma_f32_16x16x32_bf16(a[m], c0a, acc[m][0], 0, 0, 0);
            acc[m][1] = __builtin_amdgcn_mfma_f32_16x16x32_bf16(a[m], c0b, acc[m][1], 0, 0, 0);
        }
        c0a = c1a; c0b = c1b;
        if (pf) { c1a = n2a; c1b = n2b; }
        if (CIN == 64) {
            if (c & 1) { if (++dx0 == 5) { dx0 = 0; ++dy0; } }
        } else {
            dx0 += 2; if (dx0 >= 5) { dx0 -= 5; ++dy0; }
            dx1 += 2; if (dx1 >= 5) { dx1 -= 5; ++dy1; }
        }
    }
}

// ---------------------------------------------------------------------------
// One full ConvLSTM step for a (128px x 64co') tile with FUSED GATES:
//   phase1 (DOLN1 optionally fuses LayerNorm-64): W-conv ; phase2: U-conv.
//   epilogue: gate exchange via shfl_xor(8); c fp32, h bf16; fast tanh.
// ---------------------------------------------------------------------------
template<int CIN1, int PAD1, int NC1, int PRN1, bool ZR1, bool DOLN1,
         int NC2, int PRN2, int OW, int OH>
__device__ void lstm_step_core(int lblk, const short* __restrict__ in1, size_t in1_bstride,
                               int IH1, int IW1,
                               const short* __restrict__ hprev,
                               const short* __restrict__ wts, const float* __restrict__ bias,
                               const float* __restrict__ lg, const float* __restrict__ lb,
                               float* __restrict__ cbuf, short* __restrict__ hbuf,
                               int has_rec, char* smem)
{
    constexpr int PW  = OW + 4;
    constexpr int OHW = OW * OH;
    constexpr int NTIL = (OHW + 127) / 128;
    constexpr bool FULL = (OHW % 128) == 0;

    const int tid  = threadIdx.x;
    const int tile = lblk % NTIL;
    const int q    = (lblk / NTIL) & 3;
    const int n    = lblk / (NTIL * 4);
    const int p0   = tile * 128;
    const int r0   = p0 / OW;
    const int co0  = q * 64;

    const int lane = tid & 63;
    const int wid  = tid >> 6;
    const int wm   = wid >> 1;
    const int wn   = wid & 1;
    const int lr   = lane & 15;
    const int g    = lane >> 4;

    int base1[4], base2[4];
    #pragma unroll
    for (int m = 0; m < 4; ++m) {
        int px = p0 + wm * 64 + m * 16 + lr;
        int r = px / OW;
        int x = px - r * OW;
        base1[m] = ((r - r0) * PW + x) * CIN1 * 2;
        base2[m] = ((r - r0) * PW + x) * 128;
    }

    f32x4 acc[4][2];
    #pragma unroll
    for (int m = 0; m < 4; ++m)
        #pragma unroll
        for (int nn = 0; nn < 2; ++nn)
            acc[m][nn] = (f32x4){0.f, 0.f, 0.f, 0.f};

    // ---- phase 1: W-conv (optionally with fused LN on the staged input) ----
    stage_patch<CIN1, PAD1, PRN1, PW, ZR1, DOLN1>(
        smem, in1 + (size_t)n * in1_bstride, IH1, IW1, r0, lg, lb);
    __syncthreads();
    kloop<CIN1, PW, NC1>(smem, wts, co0 + wn * 32 + lr, g, base1, acc);

    // ---- phase 2: U-conv on previous h (restage same LDS) ----
    if (has_rec) {
        __syncthreads();
        stage_patch<64, 2, PRN2, PW, false, false>(
            smem, hprev + (size_t)n * OHW * 64, OH, OW, r0, nullptr, nullptr);
        __syncthreads();
        kloop<64, PW, NC2>(smem, wts + (size_t)NC1 * 8192, co0 + wn * 32 + lr, g, base2, acc);
    }

    // ---- fused gate epilogue ----
    const int fg = q * 16 + wn * 8 + (lr & 7);
    const bool low = (lr & 8) == 0;
    const float b0  = bias[(lr >> 3) * 64 + fg];         // gate 0/1 (i or f)
    const float b1v = bias[(2 + (lr >> 3)) * 64 + fg];   // gate 2/3 (cg or o)
    float* cN = cbuf + (size_t)n * OHW * 64;
    short* hN = hbuf + (size_t)n * OHW * 64;
    #pragma unroll
    for (int m = 0; m < 4; ++m) {
        int pxb = p0 + wm * 64 + m * 16 + g * 4;
        #pragma unroll
        for (int j = 0; j < 4; ++j) {
            int px = pxb + j;
            float a0 = acc[m][0][j] + b0;
            float a1 = acc[m][1][j] + b1v;
            float q0 = __shfl_xor(a0, 8);
            float q1 = __shfl_xor(a1, 8);
            float iv  = low ? a0 : q0;
            float fv  = low ? q0 : a0;
            float cgv = low ? a1 : q1;
            float ov  = low ? q1 : a1;
            bool valid = FULL || (px < OHW);
            int addr = px * 64 + fg;
            float cp = 0.f;
            if (has_rec && valid) cp = cN[addr];
            float cn = fmaf(hsig(fv), cp, hsig(iv) * tanh_fast(cgv));
            float hv = hsig(ov) * tanh_fast(cn);
            if (valid) {
                if (low) cN[addr] = cn;
                else     hN[addr] = (short)f2bf(hv);
            }
        }
    }
}

// ---------------------------------------------------------------------------
// Merged step kernel: blocks [0,n2) = LSTM2 step t (reads LN(h1) inline);
// blocks [n2,...) = LSTM1 step t+1.
// ---------------------------------------------------------------------------
__global__ __launch_bounds__(256, 3) void step_kernel(
    int n2, int has1, int has2,
    const short* __restrict__ h1r, const short* __restrict__ h2r, short* __restrict__ h2w,
    float* __restrict__ c2, const short* __restrict__ w2c, const float* __restrict__ b2,
    const float* __restrict__ lg2, const float* __restrict__ lb2,
    const short* __restrict__ xlnt, short* __restrict__ h1w,
    float* __restrict__ c1, const short* __restrict__ w1c, const float* __restrict__ b1)
{
    __shared__ __align__(16) char smem[46080];
    int bid = blockIdx.x;
    if (bid < n2) {
        // LSTM2: phase1 = W2 on LN(h1(t)) (36x36 VALID -> 32x32), phase2 = U2 on h2
        lstm_step_core<64, 0, 50, 8, false, true, 50, 8, 32, 32>(
            bid, h1r, 82944, 36, 36, h2r, w2c, b2, lg2, lb2, c2, h2w, has2, smem);
    } else {
        // LSTM1: phase1 = W1 on xln frame (40x40 VALID -> 36x36), phase2 = U1 on h1
        lstm_step_core<16, 0, 13, 10, true, false, 50, 9, 36, 36>(
            bid - n2, xlnt, 409600, 40, 40, h1r, w1c, b1, nullptr, nullptr,
            c1, h1w, has1, smem);
    }
}

// ---------------------------------------------------------------------------
// Final: mean over 32x32 pixels (bf16 h), dot dw[64], +db, *0.1
// ---------------------------------------------------------------------------
__global__ void pool_dot_kernel(const short* __restrict__ h, const float* __restrict__ dw,
                                const float* __restrict__ db, float* __restrict__ out)
{
    int b = blockIdx.x;
    __shared__ float sdw[64];
    if (threadIdx.x < 64) sdw[threadIdx.x] = dw[threadIdx.x];
    __syncthreads();
    float partial = 0.f;
    const short* hb = h + (size_t)b * 1024 * 64;
    for (int p = threadIdx.x; p < 1024; p += 256) {
        const short* hp = hb + (size_t)p * 64;
        #pragma unroll
        for (int f = 0; f < 64; f += 8) {
            bf16x8 hv = *(const bf16x8*)(hp + f);
            #pragma unroll
            for (int i = 0; i < 8; ++i) partial += bf2f(hv[i]) * sdw[f + i];
        }
    }
    #pragma unroll
    for (int o = 32; o > 0; o >>= 1) partial += __shfl_xor(partial, o);
    __shared__ float ws[4];
    if ((threadIdx.x & 63) == 0) ws[threadIdx.x >> 6] = partial;
    __syncthreads();
    if (threadIdx.x == 0) {
        float tot = ws[0] + ws[1] + ws[2] + ws[3];
        out[b] = (tot * (1.f / 1024.f) + db[0]) * 0.1f;
    }
}

// ---------------------------------------------------------------------------
// Orchestration: A(0) -> [ M(t) = LSTM2(t) + LSTM1(t+1) ] x15 -> C(15) -> pool.
// ONE launch per step (LN64 fused into LSTM2 staging).
// ---------------------------------------------------------------------------
extern "C" void kernel_launch(void* const* d_in, const int* in_sizes, int n_in,
                              void* d_out, int out_size, void* d_ws, size_t ws_size,
                              hipStream_t stream)
{
    const float* x   = (const float*)d_in[0];
    const float* lg1 = (const float*)d_in[1];
    const float* lb1 = (const float*)d_in[2];
    const float* W1  = (const float*)d_in[3];
    const float* U1  = (const float*)d_in[4];
    const float* b1  = (const float*)d_in[5];
    const float* lg2 = (const float*)d_in[6];
    const float* lb2 = (const float*)d_in[7];
    const float* W2  = (const float*)d_in[8];
    const float* U2  = (const float*)d_in[9];
    const float* b2  = (const float*)d_in[10];
    const float* dw  = (const float*)d_in[11];
    const float* db  = (const float*)d_in[12];
    float* out = (float*)d_out;

    constexpr int B = 8, T = 16;
    constexpr int P1 = 36 * 36, P2 = 32 * 32;

    char* wsb = (char*)d_ws;
    size_t off = 0;
    auto alloc_s = [&](size_t nshort) { short* p = (short*)(wsb + off); off += nshort * 2; return p; };
    auto alloc_f = [&](size_t nfloat) { off = (off + 15) & ~(size_t)15; float* p = (float*)(wsb + off); off += nfloat * 4; return p; };

    short* xln = alloc_s((size_t)B * T * 40 * 40 * 16);   // bf16, 6.5 MB
    short* h1a = alloc_s((size_t)B * P1 * 64);
    short* h1b = alloc_s((size_t)B * P1 * 64);
    short* h2a = alloc_s((size_t)B * P2 * 64);
    short* h2b = alloc_s((size_t)B * P2 * 64);
    short* w1c = alloc_s((size_t)63 * 8192);              // 13 W1 + 50 U1 chunks
    short* w2c = alloc_s((size_t)100 * 8192);             // 50 W2 + 50 U2 chunks
    float* c1  = alloc_f((size_t)B * P1 * 64);
    float* c2  = alloc_f((size_t)B * P2 * 64);
    // total ~20 MB

    short* h1buf[2] = { h1a, h1b };
    short* h2buf[2] = { h2a, h2b };

    // one-time transforms
    ln16_kernel<<<800, 256, 0, stream>>>(x, lg1, lb1, xln, 204800);
    prep_w_perm<<<416, 256, 0, stream>>>(W1, w1c, 400, 13);
    prep_w_perm<<<1600, 256, 0, stream>>>(U1, w1c + (size_t)13 * 8192, 1600, 50);
    prep_w_perm<<<1600, 256, 0, stream>>>(W2, w2c, 1600, 50);
    prep_w_perm<<<1600, 256, 0, stream>>>(U2, w2c + (size_t)50 * 8192, 1600, 50);

    constexpr int NB1 = 11 * 4 * B;   // 352 LSTM1 blocks
    constexpr int NB2 = 8 * 4 * B;    // 256 LSTM2 blocks

    // A(0): LSTM1 step 0 only
    step_kernel<<<NB1, 256, 0, stream>>>(
        0, 0, 0,
        h1buf[1], h2buf[1], h2buf[0], c2, w2c, b2, lg2, lb2,
        xln, h1buf[0], c1, w1c, b1);

    // M(t): LSTM2 step t (reads LN(h1(t)) inline) + LSTM1 step t+1
    for (int t = 0; t < T - 1; ++t) {
        step_kernel<<<NB2 + NB1, 256, 0, stream>>>(
            NB2, 1, (t > 0) ? 1 : 0,
            h1buf[t & 1], h2buf[(t + 1) & 1], h2buf[t & 1], c2, w2c, b2, lg2, lb2,
            xln + (size_t)(t + 1) * 25600, h1buf[(t + 1) & 1], c1, w1c, b1);
    }

    // C(15): LSTM2 final step (h1(15) is in h1buf[1])
    step_kernel<<<NB2, 256, 0, stream>>>(
        NB2, 1, 1,
        h1buf[1], h2buf[0], h2buf[1], c2, w2c, b2, lg2, lb2,
        xln, h1buf[0], c1, w1c, b1);

    pool_dot_kernel<<<B, 256, 0, stream>>>(h2buf[1], dw, db, out);
}